// Round 11
// baseline (289.695 us; speedup 1.0000x reference)
//
#include <hip/hip_runtime.h>

#define N_NODES 50000
#define E_EDGES 800000
#define R_REL 3
#define NSEG (N_NODES * R_REL)    // 150000 (dst,rel) segments
#define DH 128
#define KDIM 512                  // A row (bf16): 4 slices x [r0|r1|r2|x] (64B pieces)
#define ROWB 1024                 // bytes per A row
#define BATCHES 256
#define NCLASS 10
#define EPSV 1e-5f

#define BSHIFT 9
#define BNODES 512                // nodes per bucket
#define NBUCK ((N_NODES + BNODES - 1) / BNODES)   // 98
#define SEGB (BNODES * R_REL)     // 1536 segments per bucket
#define CAP 9216                  // LDS sort capacity (mean 8192, sigma ~90)
#define NCHUNK 128
#define CHUNK (E_EDGES / NCHUNK)  // 6250 (exact)
#define MATN (NBUCK * NCHUNK)     // 12544

// pre_kernel block partition
#define PRE_BX 3125               // build_x blocks (N*16/256)
#define PRE_H (PRE_BX + NCHUNK)   // hist blocks end
#define PRE_S (PRE_H + 67)        // setup blocks end

typedef __attribute__((ext_vector_type(8))) short short8v;
typedef __attribute__((ext_vector_type(4))) float float4v;
typedef unsigned short ushort_t;

__device__ __forceinline__ ushort_t f2bf(float f) {
    union { float f; unsigned u; } x; x.f = f;
    unsigned r = x.u + 0x7FFFu + ((x.u >> 16) & 1u);
    return (ushort_t)(r >> 16);
}
__device__ __forceinline__ float bf2f(ushort_t h) {
    union { unsigned u; float f; } x; x.u = ((unsigned)h) << 16;
    return x.f;
}
__device__ __forceinline__ float u2f(unsigned u) {
    union { unsigned u; float f; } x; x.u = u;
    return x.f;
}
__device__ __forceinline__ unsigned pack2(float lo, float hi) {
    return (unsigned)f2bf(lo) | ((unsigned)f2bf(hi) << 16);
}

// ---------------------------------------------------------------- fused pre: build_x + chunk_hist + setup
// A row k'-layout: elem k' = s*128 + p*32 + f  (s=slice, p=0..2 rel / 3 x, f=feat%32)
__global__ __launch_bounds__(256) void pre_kernel(
        const int* __restrict__ xi, const float* __restrict__ se,
        const float* __restrict__ ce, const float* __restrict__ pe,
        ushort_t* __restrict__ A,
        const int* __restrict__ ei, int* __restrict__ mat,
        const float* __restrict__ W1, const float* __restrict__ root1,
        const float* __restrict__ W2, const float* __restrict__ root2,
        ushort_t* __restrict__ Wf1, ushort_t* __restrict__ Wf2,
        const int* __restrict__ batch, int* __restrict__ bstart,
        const float* __restrict__ b1, const float* __restrict__ g1,
        const float* __restrict__ be1, const float* __restrict__ m1,
        const float* __restrict__ v1,
        const float* __restrict__ b2, const float* __restrict__ g2,
        const float* __restrict__ be2, const float* __restrict__ m2,
        const float* __restrict__ v2,
        float* __restrict__ sc1, float* __restrict__ sh1,
        float* __restrict__ sc2, float* __restrict__ sh2) {
    __shared__ int lh[NBUCK];
    int blk = blockIdx.x, t = threadIdx.x;
    if (blk < PRE_BX) {
        // ---- build x (bf16) into sliced x-pieces
        int tid = blk * 256 + t;
        int node = tid >> 4, c = tid & 15;
        int i0 = xi[node * 3 + 0];
        int i1 = xi[node * 3 + 1];
        int i2 = xi[node * 3 + 2];
        i2 = i2 < 0 ? 0 : (i2 > 24 ? 24 : i2);
        const float4* sa = reinterpret_cast<const float4*>(se + (size_t)i0 * DH + c * 8);
        const float4* sb = reinterpret_cast<const float4*>(ce + (size_t)i1 * DH + c * 8);
        const float4* sp = reinterpret_cast<const float4*>(pe + (size_t)i2 * DH + c * 8);
        short8v o;
        #pragma unroll
        for (int q = 0; q < 2; ++q) {
            float4 a = sa[q], b = sb[q], p = sp[q];
            o[q * 4 + 0] = (short)f2bf(a.x + b.x + p.x);
            o[q * 4 + 1] = (short)f2bf(a.y + b.y + p.y);
            o[q * 4 + 2] = (short)f2bf(a.z + b.z + p.z);
            o[q * 4 + 3] = (short)f2bf(a.w + b.w + p.w);
        }
        // features c*8..c*8+7 -> slice c>>2, piece p=3, sub (c&3)*8
        int elem = (c >> 2) * 128 + 96 + (c & 3) * 8;
        *reinterpret_cast<short8v*>(A + (size_t)node * KDIM + elem) = o;
    } else if (blk < PRE_H) {
        // ---- per-(chunk,bucket) histogram
        int ch = blk - PRE_BX;
        if (t < NBUCK) lh[t] = 0;
        __syncthreads();
        int base = ch * CHUNK;
        for (int i = t; i < CHUNK; i += 256)
            atomicAdd(&lh[ei[E_EDGES + base + i] >> BSHIFT], 1);
        __syncthreads();
        if (t < NBUCK) mat[t * NCHUNK + ch] = lh[t];
    } else if (blk < PRE_S) {
        // ---- setup: weight prepack (k'-permuted) + batch bounds + BN consts
        int tid = (blk - PRE_H) * 256 + t;
        if (tid < 16384) {
            int L = tid >> 13;
            int rem = tid & 8191;
            int l = rem & 63;
            int nt = (rem >> 6) & 7;
            int ks = rem >> 9;
            const float* W = L ? W2 : W1;
            const float* root = L ? root2 : root1;
            ushort_t* dst = (L ? Wf2 : Wf1) + (size_t)rem * 8;
            int col = nt * 16 + (l & 15);
            int kb = ks * 32 + (l >> 4) * 8;
            short8v o;
            #pragma unroll
            for (int j = 0; j < 8; ++j) {
                int kp = kb + j;                      // k' index
                int s = kp >> 7, rm = kp & 127;
                int pcs = rm >> 5, f = rm & 31;
                int k = pcs * 128 + s * 32 + f;       // original Wcat row
                float w = (k < 384) ? W[(size_t)k * DH + col]
                                    : root[(size_t)(k - 384) * DH + col];
                o[j] = (short)f2bf(w);
            }
            *reinterpret_cast<short8v*>(dst) = o;
        } else if (tid < 16384 + BATCHES + 1) {
            int b = tid - 16384;
            int lo = 0, hi = N_NODES;
            while (lo < hi) {
                int mid = (lo + hi) >> 1;
                if (batch[mid] < b) lo = mid + 1; else hi = mid;
            }
            bstart[b] = lo;
        } else if (tid < 16384 + 257 + DH) {
            int c = tid - 16384 - 257;
            float s = g1[c] * rsqrtf(v1[c] + EPSV);
            sc1[c] = s;
            sh1[c] = (b1[c] - m1[c]) * s + be1[c];
        } else if (tid < 16384 + 257 + 2 * DH) {
            int c = tid - 16384 - 257 - DH;
            float s = g2[c] * rsqrtf(v2[c] + EPSV);
            sc2[c] = s;
            sh2[c] = (b2[c] - m2[c]) * s + be2[c];
        }
    }
}

// ---------------------------------------------------------------- matrix exclusive scan (bucket-major)
__global__ __launch_bounds__(1024) void matscan_kernel(int* __restrict__ mat,
                                                       int* __restrict__ bbase,
                                                       int* __restrict__ offs3) {
    __shared__ int partial[1024];
    int t = threadIdx.x;
    int buf[13];
    int base = t * 13;
    int s = 0;
    #pragma unroll
    for (int j = 0; j < 13; ++j) {
        int idx = base + j;
        int v = (idx < MATN) ? mat[idx] : 0;
        buf[j] = s;
        s += v;
    }
    partial[t] = s;
    __syncthreads();
    for (int d = 1; d < 1024; d <<= 1) {
        int u = (t >= d) ? partial[t - d] : 0;
        __syncthreads();
        partial[t] += u;
        __syncthreads();
    }
    int off = (t > 0) ? partial[t - 1] : 0;
    #pragma unroll
    for (int j = 0; j < 13; ++j) {
        int idx = base + j;
        if (idx < MATN) mat[idx] = off + buf[j];
    }
    __syncthreads();
    if (t < NBUCK) bbase[t] = mat[t * NCHUNK];
    if (t == 0) { bbase[NBUCK] = E_EDGES; offs3[NSEG] = E_EDGES; }
}

// ---------------------------------------------------------------- chunk counting-sort + coalesced scatter
__global__ __launch_bounds__(512) void chunk_scatter_kernel(const int* __restrict__ ei,
                                                            const int* __restrict__ et,
                                                            const int* __restrict__ mat,
                                                            int* __restrict__ tlist) {
    __shared__ int sorted[CHUNK];
    __shared__ int lh[NBUCK];
    __shared__ int lstart[NBUCK + 1];
    __shared__ int mbase[NBUCK];
    __shared__ int scr[128];
    int t = threadIdx.x, blk = blockIdx.x;
    if (t < NBUCK) { lh[t] = 0; mbase[t] = mat[t * NCHUNK + blk]; }
    __syncthreads();
    int base = blk * CHUNK;
    for (int i = t; i < CHUNK; i += 512)
        atomicAdd(&lh[ei[E_EDGES + base + i] >> BSHIFT], 1);
    __syncthreads();
    if (t < 128) scr[t] = (t < NBUCK) ? lh[t] : 0;
    __syncthreads();
    for (int d = 1; d < 128; d <<= 1) {
        int u = 0;
        if (t < 128 && t >= d) u = scr[t - d];
        __syncthreads();
        if (t < 128) scr[t] += u;
        __syncthreads();
    }
    if (t < NBUCK) lstart[t] = scr[t] - lh[t];
    if (t == NBUCK - 1) lstart[NBUCK] = scr[t];
    __syncthreads();
    if (t < NBUCK) lh[t] = lstart[t];
    __syncthreads();
    for (int i = t; i < CHUNK; i += 512) {
        int e = base + i;
        int src = ei[e];
        int dst = ei[E_EDGES + e];
        int r = et[e];
        int b = dst >> BSHIFT;
        int ls = (dst & (BNODES - 1)) * R_REL + r;
        int p = atomicAdd(&lh[b], 1);
        sorted[p] = (ls << 16) | src;
    }
    __syncthreads();
    for (int i = t; i < CHUNK; i += 512) {
        int lo = 0, hi = NBUCK - 1;
        while (lo < hi) {
            int mid = (lo + hi + 1) >> 1;
            if (lstart[mid] <= i) lo = mid; else hi = mid - 1;
        }
        tlist[mbase[lo] + (i - lstart[lo])] = sorted[i];
    }
}

// ---------------------------------------------------------------- per-bucket local sort by (node,rel)
__global__ __launch_bounds__(512) void localsort_kernel(const int* __restrict__ tlist,
                                                        const int* __restrict__ bbase,
                                                        int* __restrict__ offs3,
                                                        int* __restrict__ elist) {
    __shared__ int hist[SEGB];
    __shared__ int scr[512];
    __shared__ int tl[CAP];
    __shared__ int el[CAP];
    int b = blockIdx.x, t = threadIdx.x;
    int ebeg = bbase[b], eend = bbase[b + 1];
    int cnt = eend - ebeg;
    int segbase = b * SEGB;
    #pragma unroll
    for (int j = 0; j < 3; ++j) hist[t + j * 512] = 0;
    __syncthreads();

    bool fit = (cnt <= CAP);
    if (fit) {
        for (int i = t; i < cnt; i += 512) {
            int pk = tlist[ebeg + i];
            tl[i] = pk;
            atomicAdd(&hist[pk >> 16], 1);
        }
    } else {
        for (int i = t; i < cnt; i += 512)
            atomicAdd(&hist[tlist[ebeg + i] >> 16], 1);
    }
    __syncthreads();
    int h0 = hist[3 * t], h1 = hist[3 * t + 1], h2 = hist[3 * t + 2];
    int s = h0 + h1 + h2;
    scr[t] = s;
    __syncthreads();
    for (int d = 1; d < 512; d <<= 1) {
        int u = (t >= d) ? scr[t - d] : 0;
        __syncthreads();
        scr[t] += u;
        __syncthreads();
    }
    int off = (t > 0) ? scr[t - 1] : 0;
    int e0 = off, e1 = off + h0, e2 = off + h0 + h1;
    {
        int sg = segbase + 3 * t;
        if (sg < NSEG)     offs3[sg]     = ebeg + e0;
        if (sg + 1 < NSEG) offs3[sg + 1] = ebeg + e1;
        if (sg + 2 < NSEG) offs3[sg + 2] = ebeg + e2;
    }
    __syncthreads();
    hist[3 * t] = e0; hist[3 * t + 1] = e1; hist[3 * t + 2] = e2;
    __syncthreads();
    // payload = src*ROWB + 192 (slice-0 x-piece base; agg adds slice*256 + lane*4)
    if (fit) {
        for (int i = t; i < cnt; i += 512) {
            int pk = tl[i];
            int pos = atomicAdd(&hist[pk >> 16], 1);
            el[pos] = (pk & 0xFFFF) * ROWB + 192;
        }
        __syncthreads();
        for (int i = t; i < cnt; i += 512)
            elist[ebeg + i] = el[i];
    } else {
        for (int i = t; i < cnt; i += 512) {
            int pk = tlist[ebeg + i];
            int pos = atomicAdd(&hist[pk >> 16], 1);
            elist[ebeg + pos] = (pk & 0xFFFF) * ROWB + 192;
        }
    }
}

// ---------------------------------------------------------------- gather aggregation: feature-sliced
// grid (3125, 4): blockIdx.y = 64B feature slice; per-slice gather working set 3.2MB -> L2-resident.
// 16 lanes per node (1 dword each), 16 nodes per block; unified seg loop + snapshots; batch-4 pipeline.
__global__ __launch_bounds__(256) void agg_kernel(const char* __restrict__ Ab,
                                                  const int* __restrict__ offs3,
                                                  const int* __restrict__ elist,
                                                  char* __restrict__ Aob) {
    int t = threadIdx.x;
    int g = t >> 4, c = t & 15;
    int n = blockIdx.x * 16 + g;              // grid.x = 3125, exact
    int sb = blockIdx.y * 256;                // slice byte base within row
    int s0 = offs3[3 * n + 0];
    int s1 = offs3[3 * n + 1];
    int s2 = offs3[3 * n + 2];
    int s3 = offs3[3 * n + 3];
    const char* gb = Ab + sb + c * 4;         // + elist[i] = src*1024 + s*256 + 192 + c*4

    float Sl = 0, Sh = 0, pl = 0, ph = 0, ql = 0, qh = 0;

    #define ACC(V) { Sl += u2f((V) << 16); Sh += u2f((V) & 0xFFFF0000u); }
    #define SNAP(E) { if ((E) == s1) { pl = Sl; ph = Sh; } \
                      if ((E) == s2) { ql = Sl; qh = Sh; } }

    int i = s0;
    int bend = s0 + ((s3 - s0) & ~3);
    if (i < bend) {
        int j0 = elist[i], j1 = elist[i + 1], j2 = elist[i + 2], j3 = elist[i + 3];
        unsigned g0 = *reinterpret_cast<const unsigned*>(gb + j0);
        unsigned g1 = *reinterpret_cast<const unsigned*>(gb + j1);
        unsigned g2 = *reinterpret_cast<const unsigned*>(gb + j2);
        unsigned g3 = *reinterpret_cast<const unsigned*>(gb + j3);
        for (;;) {
            int inx = i + 4;
            bool more = inx < bend;
            unsigned h0 = 0, h1 = 0, h2 = 0, h3 = 0;
            if (more) {
                int k0 = elist[inx], k1 = elist[inx + 1];
                int k2 = elist[inx + 2], k3 = elist[inx + 3];
                h0 = *reinterpret_cast<const unsigned*>(gb + k0);
                h1 = *reinterpret_cast<const unsigned*>(gb + k1);
                h2 = *reinterpret_cast<const unsigned*>(gb + k2);
                h3 = *reinterpret_cast<const unsigned*>(gb + k3);
            }
            SNAP(i)     ACC(g0)
            SNAP(i + 1) ACC(g1)
            SNAP(i + 2) ACC(g2)
            SNAP(i + 3) ACC(g3)
            if (!more) break;
            g0 = h0; g1 = h1; g2 = h2; g3 = h3;
            i = inx;
        }
        i = bend;
    }
    for (; i < s3; ++i) {
        unsigned v = *reinterpret_cast<const unsigned*>(gb + elist[i]);
        SNAP(i)
        ACC(v)
    }
    if (s1 == s3) { pl = Sl; ph = Sh; }
    if (s2 == s3) { ql = Sl; qh = Sh; }
    #undef ACC
    #undef SNAP

    int c0 = s1 - s0, c1 = s2 - s1, c2 = s3 - s2;
    float i0 = c0 ? 1.f / c0 : 0.f;
    float i1 = c1 ? 1.f / c1 : 0.f;
    float i2 = c2 ? 1.f / c2 : 0.f;
    char* base = Aob + (size_t)n * ROWB + sb + c * 4;
    *reinterpret_cast<unsigned*>(base + 0)   = pack2(pl * i0, ph * i0);
    *reinterpret_cast<unsigned*>(base + 64)  = pack2((ql - pl) * i1, (qh - ph) * i1);
    *reinterpret_cast<unsigned*>(base + 128) = pack2((Sl - ql) * i2, (Sh - qh) * i2);
}

// ---------------------------------------------------------------- MFMA GEMM + BN + ReLU
// 32 rows/wave (2 row-tiles share each B-frag -> half the weight stream), 128 rows/block.
// sliced=1: write h into x-pieces of A (k'-layout); sliced=0: compact [N][DH] out.
__global__ __launch_bounds__(256) void gemm_mfma_kernel(const ushort_t* __restrict__ A,
                                                        const ushort_t* __restrict__ Wf,
                                                        const float* __restrict__ sc,
                                                        const float* __restrict__ sh,
                                                        ushort_t* __restrict__ Aout,
                                                        int sliced) {
    int w = threadIdx.x >> 6, l = threadIdx.x & 63;
    int base = blockIdx.x * 128 + w * 32;
    int ra = base + (l & 15);
    int rb = ra + 16;
    int rac = ra >= N_NODES ? N_NODES - 1 : ra;
    int rbc = rb >= N_NODES ? N_NODES - 1 : rb;
    const short8v* apa = reinterpret_cast<const short8v*>(A + (size_t)rac * KDIM + (l >> 4) * 8);
    const short8v* apb = reinterpret_cast<const short8v*>(A + (size_t)rbc * KDIM + (l >> 4) * 8);
    const short8v* wf = reinterpret_cast<const short8v*>(Wf) + l;

    float4v acc0[8], acc1[8];
    #pragma unroll
    for (int nt = 0; nt < 8; ++nt) {
        acc0[nt] = (float4v){0.f, 0.f, 0.f, 0.f};
        acc1[nt] = (float4v){0.f, 0.f, 0.f, 0.f};
    }

    #pragma unroll 4
    for (int ks = 0; ks < 16; ++ks) {
        short8v a0 = apa[ks * 4];
        short8v a1 = apb[ks * 4];
        const short8v* bp = wf + ks * 512;
        #pragma unroll
        for (int nt = 0; nt < 8; ++nt) {
            short8v b = bp[nt * 64];
            acc0[nt] = __builtin_amdgcn_mfma_f32_16x16x32_bf16(a0, b, acc0[nt], 0, 0, 0);
            acc1[nt] = __builtin_amdgcn_mfma_f32_16x16x32_bf16(a1, b, acc1[nt], 0, 0, 0);
        }
    }

    int colb = l & 15;
    int rowq = (l >> 4) * 4;
    int ostride = sliced ? KDIM : DH;
    #pragma unroll
    for (int nt = 0; nt < 8; ++nt) {
        int col = nt * 16 + colb;
        int off = sliced ? ((col >> 5) * 128 + 96 + (col & 31)) : col;
        float scv = sc[col], shv = sh[col];
        #pragma unroll
        for (int r = 0; r < 4; ++r) {
            int row0 = base + rowq + r;
            int row1 = row0 + 16;
            if (row0 < N_NODES) {
                float v0 = fmaxf(acc0[nt][r] * scv + shv, 0.f);
                Aout[(size_t)row0 * ostride + off] = f2bf(v0);
            }
            if (row1 < N_NODES) {
                float v1 = fmaxf(acc1[nt][r] * scv + shv, 0.f);
                Aout[(size_t)row1 * ostride + off] = f2bf(v1);
            }
        }
    }
}

// ---------------------------------------------------------------- fused global-mean-pool + classifier
__global__ __launch_bounds__(256) void pool_cls_kernel(
        const ushort_t* __restrict__ h,             // compact [N][DH] bf16
        const int* __restrict__ bstart,
        const float* __restrict__ clsW,
        const float* __restrict__ clsb,
        float* __restrict__ out) {
    __shared__ float hsh[DH];
    int b = blockIdx.x;
    int t = threadIdx.x;
    int c = t & 127;
    int half = t >> 7;
    int beg = bstart[b], end = bstart[b + 1];
    float s = 0.f;
    for (int n = beg + half; n < end; n += 2)
        s += bf2f(h[(size_t)n * DH + c]);
    if (half == 1) hsh[c] = s;
    __syncthreads();
    if (half == 0) {
        float cnt = (float)(end - beg);
        float inv = cnt > 0.f ? 1.f / cnt : 1.f;
        hsh[c] = (s + hsh[c]) * inv;
    }
    __syncthreads();
    if (t < NCLASS) {
        float acc = clsb[t];
        #pragma unroll 16
        for (int d = 0; d < DH; ++d)
            acc += hsh[d] * clsW[d * NCLASS + t];
        out[b * NCLASS + t] = acc;
    }
}

// ---------------------------------------------------------------- launch
extern "C" void kernel_launch(void* const* d_in, const int* in_sizes, int n_in,
                              void* d_out, int out_size, void* d_ws, size_t ws_size,
                              hipStream_t stream) {
    const int*   x_idx  = (const int*)d_in[0];
    const int*   eidx   = (const int*)d_in[1];
    const int*   etype  = (const int*)d_in[2];
    const int*   batch  = (const int*)d_in[3];
    const float* se     = (const float*)d_in[4];
    const float* ce     = (const float*)d_in[5];
    const float* pe     = (const float*)d_in[6];
    const float* W1     = (const float*)d_in[7];
    const float* root1  = (const float*)d_in[8];
    const float* b1     = (const float*)d_in[9];
    const float* g1     = (const float*)d_in[10];
    const float* beta1  = (const float*)d_in[11];
    const float* m1     = (const float*)d_in[12];
    const float* v1     = (const float*)d_in[13];
    const float* W2     = (const float*)d_in[14];
    const float* root2  = (const float*)d_in[15];
    const float* b2     = (const float*)d_in[16];
    const float* g2     = (const float*)d_in[17];
    const float* beta2  = (const float*)d_in[18];
    const float* m2     = (const float*)d_in[19];
    const float* v2     = (const float*)d_in[20];
    const float* clsW   = (const float*)d_in[21];
    const float* clsb   = (const float*)d_in[22];
    float* out = (float*)d_out;

    // workspace layout (16B-aligned blocks)
    char* ws = (char*)d_ws;
    const size_t A_bytes     = (size_t)N_NODES * KDIM * 2;   // 51,200,000
    const size_t elist_bytes = (size_t)E_EDGES * 4;          //  3,200,000
    const size_t tlist_bytes = (size_t)E_EDGES * 4;          //  3,200,000
    const size_t offs3_pad   = 600064;                       // (NSEG+1)*4 padded
    ushort_t* A      = (ushort_t*)(ws);
    int*      elist  = (int*)(ws + A_bytes);
    int*      tlist  = (int*)(ws + A_bytes + elist_bytes);
    int*      offs3  = (int*)(ws + A_bytes + elist_bytes + tlist_bytes);
    char*     p      = ws + A_bytes + elist_bytes + tlist_bytes + offs3_pad;
    int*      mat    = (int*)p;            p += 50176;       // 12544 ints
    int*      bbase  = (int*)p;            p += 512;
    int*      bstart = (int*)p;            p += 1088;
    ushort_t* Wf1    = (ushort_t*)p;       p += 131072;
    ushort_t* Wf2    = (ushort_t*)p;       p += 131072;
    float*    sc1    = (float*)p;          p += 512;
    float*    sh1    = (float*)p;          p += 512;
    float*    sc2    = (float*)p;          p += 512;
    float*    sh2    = (float*)p;          p += 512;
    ushort_t* H2     = (ushort_t*)p;       p += (size_t)N_NODES * DH * 2;   // 12.8 MB

    // fused pre: build_x + chunk_hist + setup
    pre_kernel<<<PRE_S, 256, 0, stream>>>(x_idx, se, ce, pe, A,
                                          eidx, mat,
                                          W1, root1, W2, root2, Wf1, Wf2,
                                          batch, bstart,
                                          b1, g1, beta1, m1, v1,
                                          b2, g2, beta2, m2, v2,
                                          sc1, sh1, sc2, sh2);

    // chunked counting-sort CSR build
    matscan_kernel<<<1, 1024, 0, stream>>>(mat, bbase, offs3);
    chunk_scatter_kernel<<<NCHUNK, 512, 0, stream>>>(eidx, etype, mat, tlist);
    localsort_kernel<<<NBUCK, 512, 0, stream>>>(tlist, bbase, offs3, elist);

    // ----- layer 1
    agg_kernel<<<dim3(N_NODES / 16, 4), 256, 0, stream>>>((const char*)A, offs3, elist, (char*)A);
    gemm_mfma_kernel<<<(N_NODES + 127) / 128, 256, 0, stream>>>(A, Wf1, sc1, sh1, A, 1);

    // ----- layer 2
    agg_kernel<<<dim3(N_NODES / 16, 4), 256, 0, stream>>>((const char*)A, offs3, elist, (char*)A);
    gemm_mfma_kernel<<<(N_NODES + 127) / 128, 256, 0, stream>>>(A, Wf2, sc2, sh2, H2, 0);

    // ----- fused global mean pool + classifier (compact h2)
    pool_cls_kernel<<<BATCHES, 256, 0, stream>>>(H2, bstart, clsW, clsb, out);
}

// Round 12
// 251.203 us; speedup vs baseline: 1.1532x; 1.1532x over previous
//
#include <hip/hip_runtime.h>

#define N_NODES 50000
#define E_EDGES 800000
#define R_REL 3
#define NSEG (N_NODES * R_REL)    // 150000 (dst,rel) segments
#define DH 128
#define KDIM 512                  // A row: [mean_r0 | mean_r1 | mean_r2 | x/h] in bf16
#define ROWB 1024                 // bytes per A row
#define XOFF (3 * DH * 2)         // byte offset of x/h slot (768)
#define BATCHES 256
#define NCLASS 10
#define EPSV 1e-5f

#define BSHIFT 9
#define BNODES 512                // nodes per bucket
#define NBUCK ((N_NODES + BNODES - 1) / BNODES)   // 98
#define SEGB (BNODES * R_REL)     // 1536 segments per bucket
#define CAP 9216                  // LDS sort capacity (mean 8192, sigma ~90)
#define NCHUNK 128
#define CHUNK (E_EDGES / NCHUNK)  // 6250 (exact)
#define MATN (NBUCK * NCHUNK)     // 12544

// pre_kernel block partition
#define PRE_BX 3125               // build_x blocks (N*16/256)
#define PRE_H (PRE_BX + NCHUNK)   // hist blocks end
#define PRE_S (PRE_H + 67)        // setup blocks end

typedef __attribute__((ext_vector_type(8))) short short8v;
typedef __attribute__((ext_vector_type(4))) unsigned uint4v;
typedef __attribute__((ext_vector_type(4))) float float4v;
typedef unsigned short ushort_t;

__device__ __forceinline__ ushort_t f2bf(float f) {
    union { float f; unsigned u; } x; x.f = f;
    unsigned r = x.u + 0x7FFFu + ((x.u >> 16) & 1u);
    return (ushort_t)(r >> 16);
}
__device__ __forceinline__ float bf2f(ushort_t h) {
    union { unsigned u; float f; } x; x.u = ((unsigned)h) << 16;
    return x.f;
}
__device__ __forceinline__ float u2f(unsigned u) {
    union { unsigned u; float f; } x; x.u = u;
    return x.f;
}

// ---------------------------------------------------------------- fused pre: build_x + chunk_hist + setup
__global__ __launch_bounds__(256) void pre_kernel(
        const int* __restrict__ xi, const float* __restrict__ se,
        const float* __restrict__ ce, const float* __restrict__ pe,
        ushort_t* __restrict__ A,
        const int* __restrict__ ei, int* __restrict__ mat,
        const float* __restrict__ W1, const float* __restrict__ root1,
        const float* __restrict__ W2, const float* __restrict__ root2,
        ushort_t* __restrict__ Wf1, ushort_t* __restrict__ Wf2,
        const int* __restrict__ batch, int* __restrict__ bstart,
        const float* __restrict__ b1, const float* __restrict__ g1,
        const float* __restrict__ be1, const float* __restrict__ m1,
        const float* __restrict__ v1,
        const float* __restrict__ b2, const float* __restrict__ g2,
        const float* __restrict__ be2, const float* __restrict__ m2,
        const float* __restrict__ v2,
        float* __restrict__ sc1, float* __restrict__ sh1,
        float* __restrict__ sc2, float* __restrict__ sh2) {
    __shared__ int lh[NBUCK];
    int blk = blockIdx.x, t = threadIdx.x;
    if (blk < PRE_BX) {
        // ---- build x (bf16) into A x-slot
        int tid = blk * 256 + t;
        int node = tid >> 4, c = tid & 15;
        int i0 = xi[node * 3 + 0];
        int i1 = xi[node * 3 + 1];
        int i2 = xi[node * 3 + 2];
        i2 = i2 < 0 ? 0 : (i2 > 24 ? 24 : i2);
        const float4* sa = reinterpret_cast<const float4*>(se + (size_t)i0 * DH + c * 8);
        const float4* sb = reinterpret_cast<const float4*>(ce + (size_t)i1 * DH + c * 8);
        const float4* sp = reinterpret_cast<const float4*>(pe + (size_t)i2 * DH + c * 8);
        short8v o;
        #pragma unroll
        for (int q = 0; q < 2; ++q) {
            float4 a = sa[q], b = sb[q], p = sp[q];
            o[q * 4 + 0] = (short)f2bf(a.x + b.x + p.x);
            o[q * 4 + 1] = (short)f2bf(a.y + b.y + p.y);
            o[q * 4 + 2] = (short)f2bf(a.z + b.z + p.z);
            o[q * 4 + 3] = (short)f2bf(a.w + b.w + p.w);
        }
        *reinterpret_cast<short8v*>(A + (size_t)node * KDIM + 3 * DH + c * 8) = o;
    } else if (blk < PRE_H) {
        // ---- per-(chunk,bucket) histogram
        int ch = blk - PRE_BX;
        if (t < NBUCK) lh[t] = 0;
        __syncthreads();
        int base = ch * CHUNK;
        for (int i = t; i < CHUNK; i += 256)
            atomicAdd(&lh[ei[E_EDGES + base + i] >> BSHIFT], 1);
        __syncthreads();
        if (t < NBUCK) mat[t * NCHUNK + ch] = lh[t];
    } else if (blk < PRE_S) {
        // ---- setup: weight prepack + batch bounds + BN consts
        int tid = (blk - PRE_H) * 256 + t;
        if (tid < 16384) {
            int L = tid >> 13;
            int rem = tid & 8191;
            int l = rem & 63;
            int nt = (rem >> 6) & 7;
            int ks = rem >> 9;
            const float* W = L ? W2 : W1;
            const float* root = L ? root2 : root1;
            ushort_t* dst = (L ? Wf2 : Wf1) + (size_t)rem * 8;
            int col = nt * 16 + (l & 15);
            int kb = ks * 32 + (l >> 4) * 8;
            short8v o;
            #pragma unroll
            for (int j = 0; j < 8; ++j) {
                int k = kb + j;
                float w = (k < 384) ? W[(size_t)k * DH + col]
                                    : root[(size_t)(k - 384) * DH + col];
                o[j] = (short)f2bf(w);
            }
            *reinterpret_cast<short8v*>(dst) = o;
        } else if (tid < 16384 + BATCHES + 1) {
            int b = tid - 16384;
            int lo = 0, hi = N_NODES;
            while (lo < hi) {
                int mid = (lo + hi) >> 1;
                if (batch[mid] < b) lo = mid + 1; else hi = mid;
            }
            bstart[b] = lo;
        } else if (tid < 16384 + 257 + DH) {
            int c = tid - 16384 - 257;
            float s = g1[c] * rsqrtf(v1[c] + EPSV);
            sc1[c] = s;
            sh1[c] = (b1[c] - m1[c]) * s + be1[c];
        } else if (tid < 16384 + 257 + 2 * DH) {
            int c = tid - 16384 - 257 - DH;
            float s = g2[c] * rsqrtf(v2[c] + EPSV);
            sc2[c] = s;
            sh2[c] = (b2[c] - m2[c]) * s + be2[c];
        }
    }
}

// ---------------------------------------------------------------- matrix exclusive scan (bucket-major)
__global__ __launch_bounds__(1024) void matscan_kernel(int* __restrict__ mat,
                                                       int* __restrict__ bbase,
                                                       int* __restrict__ offs3) {
    __shared__ int partial[1024];
    int t = threadIdx.x;
    int buf[13];
    int base = t * 13;
    int s = 0;
    #pragma unroll
    for (int j = 0; j < 13; ++j) {
        int idx = base + j;
        int v = (idx < MATN) ? mat[idx] : 0;
        buf[j] = s;
        s += v;
    }
    partial[t] = s;
    __syncthreads();
    for (int d = 1; d < 1024; d <<= 1) {
        int u = (t >= d) ? partial[t - d] : 0;
        __syncthreads();
        partial[t] += u;
        __syncthreads();
    }
    int off = (t > 0) ? partial[t - 1] : 0;
    #pragma unroll
    for (int j = 0; j < 13; ++j) {
        int idx = base + j;
        if (idx < MATN) mat[idx] = off + buf[j];
    }
    __syncthreads();
    if (t < NBUCK) bbase[t] = mat[t * NCHUNK];
    if (t == 0) { bbase[NBUCK] = E_EDGES; offs3[NSEG] = E_EDGES; }
}

// ---------------------------------------------------------------- chunk counting-sort + coalesced scatter
__global__ __launch_bounds__(512) void chunk_scatter_kernel(const int* __restrict__ ei,
                                                            const int* __restrict__ et,
                                                            const int* __restrict__ mat,
                                                            int* __restrict__ tlist) {
    __shared__ int sorted[CHUNK];
    __shared__ int lh[NBUCK];
    __shared__ int lstart[NBUCK + 1];
    __shared__ int mbase[NBUCK];
    __shared__ int scr[128];
    int t = threadIdx.x, blk = blockIdx.x;
    if (t < NBUCK) { lh[t] = 0; mbase[t] = mat[t * NCHUNK + blk]; }
    __syncthreads();
    int base = blk * CHUNK;
    for (int i = t; i < CHUNK; i += 512)
        atomicAdd(&lh[ei[E_EDGES + base + i] >> BSHIFT], 1);
    __syncthreads();
    if (t < 128) scr[t] = (t < NBUCK) ? lh[t] : 0;
    __syncthreads();
    for (int d = 1; d < 128; d <<= 1) {
        int u = 0;
        if (t < 128 && t >= d) u = scr[t - d];
        __syncthreads();
        if (t < 128) scr[t] += u;
        __syncthreads();
    }
    if (t < NBUCK) lstart[t] = scr[t] - lh[t];
    if (t == NBUCK - 1) lstart[NBUCK] = scr[t];
    __syncthreads();
    if (t < NBUCK) lh[t] = lstart[t];
    __syncthreads();
    for (int i = t; i < CHUNK; i += 512) {
        int e = base + i;
        int src = ei[e];
        int dst = ei[E_EDGES + e];
        int r = et[e];
        int b = dst >> BSHIFT;
        int ls = (dst & (BNODES - 1)) * R_REL + r;
        int p = atomicAdd(&lh[b], 1);
        sorted[p] = (ls << 16) | src;
    }
    __syncthreads();
    for (int i = t; i < CHUNK; i += 512) {
        int lo = 0, hi = NBUCK - 1;
        while (lo < hi) {
            int mid = (lo + hi + 1) >> 1;
            if (lstart[mid] <= i) lo = mid; else hi = mid - 1;
        }
        tlist[mbase[lo] + (i - lstart[lo])] = sorted[i];
    }
}

// ---------------------------------------------------------------- per-bucket local sort by (node,rel)
__global__ __launch_bounds__(512) void localsort_kernel(const int* __restrict__ tlist,
                                                        const int* __restrict__ bbase,
                                                        int* __restrict__ offs3,
                                                        int* __restrict__ elist) {
    __shared__ int hist[SEGB];
    __shared__ int scr[512];
    __shared__ int tl[CAP];
    __shared__ int el[CAP];
    int b = blockIdx.x, t = threadIdx.x;
    int ebeg = bbase[b], eend = bbase[b + 1];
    int cnt = eend - ebeg;
    int segbase = b * SEGB;
    #pragma unroll
    for (int j = 0; j < 3; ++j) hist[t + j * 512] = 0;
    __syncthreads();

    bool fit = (cnt <= CAP);
    if (fit) {
        for (int i = t; i < cnt; i += 512) {
            int pk = tlist[ebeg + i];
            tl[i] = pk;
            atomicAdd(&hist[pk >> 16], 1);
        }
    } else {
        for (int i = t; i < cnt; i += 512)
            atomicAdd(&hist[tlist[ebeg + i] >> 16], 1);
    }
    __syncthreads();
    int h0 = hist[3 * t], h1 = hist[3 * t + 1], h2 = hist[3 * t + 2];
    int s = h0 + h1 + h2;
    scr[t] = s;
    __syncthreads();
    for (int d = 1; d < 512; d <<= 1) {
        int u = (t >= d) ? scr[t - d] : 0;
        __syncthreads();
        scr[t] += u;
        __syncthreads();
    }
    int off = (t > 0) ? scr[t - 1] : 0;
    int e0 = off, e1 = off + h0, e2 = off + h0 + h1;
    {
        int sg = segbase + 3 * t;
        if (sg < NSEG)     offs3[sg]     = ebeg + e0;
        if (sg + 1 < NSEG) offs3[sg + 1] = ebeg + e1;
        if (sg + 2 < NSEG) offs3[sg + 2] = ebeg + e2;
    }
    __syncthreads();
    hist[3 * t] = e0; hist[3 * t + 1] = e1; hist[3 * t + 2] = e2;
    __syncthreads();
    if (fit) {
        for (int i = t; i < cnt; i += 512) {
            int pk = tl[i];
            int pos = atomicAdd(&hist[pk >> 16], 1);
            el[pos] = (pk & 0xFFFF) * ROWB + XOFF;
        }
        __syncthreads();
        for (int i = t; i < cnt; i += 512)
            elist[ebeg + i] = el[i];
    } else {
        for (int i = t; i < cnt; i += 512) {
            int pk = tlist[ebeg + i];
            int pos = atomicAdd(&hist[pk >> 16], 1);
            elist[ebeg + pos] = (pk & 0xFFFF) * ROWB + XOFF;
        }
    }
}

// ---------------------------------------------------------------- gather aggregation: per-rel means
// 16 lanes per node (16B each), 16 nodes per 256-thr block. Unified loop over all 3
// segments, running-sum snapshots at rel boundaries, batch-4 index+gather pipeline.
__global__ __launch_bounds__(256) void agg_kernel(const char* __restrict__ Ab,
                                                  const int* __restrict__ offs3,
                                                  const int* __restrict__ elist,
                                                  char* __restrict__ Aob) {
    int t = threadIdx.x;
    int g = t >> 4, c = t & 15;
    int n = blockIdx.x * 16 + g;              // grid 3125, exact
    int s0 = offs3[3 * n + 0];
    int s1 = offs3[3 * n + 1];
    int s2 = offs3[3 * n + 2];
    int s3 = offs3[3 * n + 3];
    int cb = c * 16;

    float S0 = 0, S1 = 0, S2 = 0, S3 = 0, S4 = 0, S5 = 0, S6 = 0, S7 = 0;
    float p0 = 0, p1 = 0, p2 = 0, p3 = 0, p4 = 0, p5 = 0, p6 = 0, p7 = 0;
    float q0 = 0, q1 = 0, q2 = 0, q3 = 0, q4 = 0, q5 = 0, q6 = 0, q7 = 0;

    #define ACC8(V)                                           \
        S0 += u2f(V[0] << 16); S1 += u2f(V[0] & 0xFFFF0000u); \
        S2 += u2f(V[1] << 16); S3 += u2f(V[1] & 0xFFFF0000u); \
        S4 += u2f(V[2] << 16); S5 += u2f(V[2] & 0xFFFF0000u); \
        S6 += u2f(V[3] << 16); S7 += u2f(V[3] & 0xFFFF0000u);
    #define SNAPCHK(E)                                                              \
        if ((E) == s1) { p0=S0; p1=S1; p2=S2; p3=S3; p4=S4; p5=S5; p6=S6; p7=S7; }  \
        if ((E) == s2) { q0=S0; q1=S1; q2=S2; q3=S3; q4=S4; q5=S5; q6=S6; q7=S7; }

    int i = s0;
    int bend = s0 + ((s3 - s0) & ~3);
    if (i < bend) {
        int j0 = elist[i], j1 = elist[i + 1], j2 = elist[i + 2], j3 = elist[i + 3];
        uint4v g0 = *reinterpret_cast<const uint4v*>(Ab + j0 + cb);
        uint4v g1 = *reinterpret_cast<const uint4v*>(Ab + j1 + cb);
        uint4v g2 = *reinterpret_cast<const uint4v*>(Ab + j2 + cb);
        uint4v g3 = *reinterpret_cast<const uint4v*>(Ab + j3 + cb);
        for (;;) {
            int inx = i + 4;
            bool more = inx < bend;
            uint4v h0, h1, h2, h3;
            if (more) {
                int k0 = elist[inx], k1 = elist[inx + 1], k2 = elist[inx + 2], k3 = elist[inx + 3];
                h0 = *reinterpret_cast<const uint4v*>(Ab + k0 + cb);
                h1 = *reinterpret_cast<const uint4v*>(Ab + k1 + cb);
                h2 = *reinterpret_cast<const uint4v*>(Ab + k2 + cb);
                h3 = *reinterpret_cast<const uint4v*>(Ab + k3 + cb);
            }
            SNAPCHK(i)     ACC8(g0)
            SNAPCHK(i + 1) ACC8(g1)
            SNAPCHK(i + 2) ACC8(g2)
            SNAPCHK(i + 3) ACC8(g3)
            if (!more) break;
            g0 = h0; g1 = h1; g2 = h2; g3 = h3;
            i = inx;
        }
        i = bend;
    }
    for (; i < s3; ++i) {
        int j = elist[i];
        uint4v v = *reinterpret_cast<const uint4v*>(Ab + j + cb);
        SNAPCHK(i)
        ACC8(v)
    }
    if (s1 == s3) { p0=S0; p1=S1; p2=S2; p3=S3; p4=S4; p5=S5; p6=S6; p7=S7; }
    if (s2 == s3) { q0=S0; q1=S1; q2=S2; q3=S3; q4=S4; q5=S5; q6=S6; q7=S7; }
    #undef ACC8
    #undef SNAPCHK

    int c0 = s1 - s0, c1 = s2 - s1, c2 = s3 - s2;
    float i0 = c0 ? 1.f / c0 : 0.f;
    float i1 = c1 ? 1.f / c1 : 0.f;
    float i2 = c2 ? 1.f / c2 : 0.f;
    char* base = Aob + (size_t)n * ROWB + cb;
    uint4v o;
    o[0] = (unsigned)f2bf(p0 * i0) | ((unsigned)f2bf(p1 * i0) << 16);
    o[1] = (unsigned)f2bf(p2 * i0) | ((unsigned)f2bf(p3 * i0) << 16);
    o[2] = (unsigned)f2bf(p4 * i0) | ((unsigned)f2bf(p5 * i0) << 16);
    o[3] = (unsigned)f2bf(p6 * i0) | ((unsigned)f2bf(p7 * i0) << 16);
    *reinterpret_cast<uint4v*>(base + 0 * 256) = o;
    o[0] = (unsigned)f2bf((q0 - p0) * i1) | ((unsigned)f2bf((q1 - p1) * i1) << 16);
    o[1] = (unsigned)f2bf((q2 - p2) * i1) | ((unsigned)f2bf((q3 - p3) * i1) << 16);
    o[2] = (unsigned)f2bf((q4 - p4) * i1) | ((unsigned)f2bf((q5 - p5) * i1) << 16);
    o[3] = (unsigned)f2bf((q6 - p6) * i1) | ((unsigned)f2bf((q7 - p7) * i1) << 16);
    *reinterpret_cast<uint4v*>(base + 1 * 256) = o;
    o[0] = (unsigned)f2bf((S0 - q0) * i2) | ((unsigned)f2bf((S1 - q1) * i2) << 16);
    o[1] = (unsigned)f2bf((S2 - q2) * i2) | ((unsigned)f2bf((S3 - q3) * i2) << 16);
    o[2] = (unsigned)f2bf((S4 - q4) * i2) | ((unsigned)f2bf((S5 - q5) * i2) << 16);
    o[3] = (unsigned)f2bf((S6 - q6) * i2) | ((unsigned)f2bf((S7 - q7) * i2) << 16);
    *reinterpret_cast<uint4v*>(base + 2 * 256) = o;
}

// ---------------------------------------------------------------- MFMA GEMM + BN + ReLU
// 32 rows/wave (2 row-tiles share each B-frag -> half the weight stream), 128 rows/block.
__global__ __launch_bounds__(256) void gemm_mfma_kernel(const ushort_t* __restrict__ A,
                                                        const ushort_t* __restrict__ Wf,
                                                        const float* __restrict__ sc,
                                                        const float* __restrict__ sh,
                                                        ushort_t* __restrict__ Aout,
                                                        int ostride, int ooff) {
    int w = threadIdx.x >> 6, l = threadIdx.x & 63;
    int base = blockIdx.x * 128 + w * 32;
    int ra = base + (l & 15);
    int rb = ra + 16;
    int rac = ra >= N_NODES ? N_NODES - 1 : ra;
    int rbc = rb >= N_NODES ? N_NODES - 1 : rb;
    const short8v* apa = reinterpret_cast<const short8v*>(A + (size_t)rac * KDIM + (l >> 4) * 8);
    const short8v* apb = reinterpret_cast<const short8v*>(A + (size_t)rbc * KDIM + (l >> 4) * 8);
    const short8v* wf = reinterpret_cast<const short8v*>(Wf) + l;

    float4v acc0[8], acc1[8];
    #pragma unroll
    for (int nt = 0; nt < 8; ++nt) {
        acc0[nt] = (float4v){0.f, 0.f, 0.f, 0.f};
        acc1[nt] = (float4v){0.f, 0.f, 0.f, 0.f};
    }

    #pragma unroll 4
    for (int ks = 0; ks < 16; ++ks) {
        short8v a0 = apa[ks * 4];
        short8v a1 = apb[ks * 4];
        const short8v* bp = wf + ks * 512;
        #pragma unroll
        for (int nt = 0; nt < 8; ++nt) {
            short8v b = bp[nt * 64];
            acc0[nt] = __builtin_amdgcn_mfma_f32_16x16x32_bf16(a0, b, acc0[nt], 0, 0, 0);
            acc1[nt] = __builtin_amdgcn_mfma_f32_16x16x32_bf16(a1, b, acc1[nt], 0, 0, 0);
        }
    }

    int colb = l & 15;
    int rowq = (l >> 4) * 4;
    #pragma unroll
    for (int nt = 0; nt < 8; ++nt) {
        int col = nt * 16 + colb;
        float scv = sc[col], shv = sh[col];
        #pragma unroll
        for (int r = 0; r < 4; ++r) {
            int row0 = base + rowq + r;
            int row1 = row0 + 16;
            if (row0 < N_NODES) {
                float v0 = fmaxf(acc0[nt][r] * scv + shv, 0.f);
                Aout[(size_t)row0 * ostride + ooff + col] = f2bf(v0);
            }
            if (row1 < N_NODES) {
                float v1 = fmaxf(acc1[nt][r] * scv + shv, 0.f);
                Aout[(size_t)row1 * ostride + ooff + col] = f2bf(v1);
            }
        }
    }
}

// ---------------------------------------------------------------- fused global-mean-pool + classifier
__global__ __launch_bounds__(256) void pool_cls_kernel(
        const ushort_t* __restrict__ h,             // compact [N][DH] bf16
        const int* __restrict__ bstart,
        const float* __restrict__ clsW,
        const float* __restrict__ clsb,
        float* __restrict__ out) {
    __shared__ float hsh[DH];
    int b = blockIdx.x;
    int t = threadIdx.x;
    int c = t & 127;
    int half = t >> 7;
    int beg = bstart[b], end = bstart[b + 1];
    float s = 0.f;
    for (int n = beg + half; n < end; n += 2)
        s += bf2f(h[(size_t)n * DH + c]);
    if (half == 1) hsh[c] = s;
    __syncthreads();
    if (half == 0) {
        float cnt = (float)(end - beg);
        float inv = cnt > 0.f ? 1.f / cnt : 1.f;
        hsh[c] = (s + hsh[c]) * inv;
    }
    __syncthreads();
    if (t < NCLASS) {
        float acc = clsb[t];
        #pragma unroll 16
        for (int d = 0; d < DH; ++d)
            acc += hsh[d] * clsW[d * NCLASS + t];
        out[b * NCLASS + t] = acc;
    }
}

// ---------------------------------------------------------------- launch
extern "C" void kernel_launch(void* const* d_in, const int* in_sizes, int n_in,
                              void* d_out, int out_size, void* d_ws, size_t ws_size,
                              hipStream_t stream) {
    const int*   x_idx  = (const int*)d_in[0];
    const int*   eidx   = (const int*)d_in[1];
    const int*   etype  = (const int*)d_in[2];
    const int*   batch  = (const int*)d_in[3];
    const float* se     = (const float*)d_in[4];
    const float* ce     = (const float*)d_in[5];
    const float* pe     = (const float*)d_in[6];
    const float* W1     = (const float*)d_in[7];
    const float* root1  = (const float*)d_in[8];
    const float* b1     = (const float*)d_in[9];
    const float* g1     = (const float*)d_in[10];
    const float* beta1  = (const float*)d_in[11];
    const float* m1     = (const float*)d_in[12];
    const float* v1     = (const float*)d_in[13];
    const float* W2     = (const float*)d_in[14];
    const float* root2  = (const float*)d_in[15];
    const float* b2     = (const float*)d_in[16];
    const float* g2     = (const float*)d_in[17];
    const float* beta2  = (const float*)d_in[18];
    const float* m2     = (const float*)d_in[19];
    const float* v2     = (const float*)d_in[20];
    const float* clsW   = (const float*)d_in[21];
    const float* clsb   = (const float*)d_in[22];
    float* out = (float*)d_out;

    // workspace layout (16B-aligned blocks)
    char* ws = (char*)d_ws;
    const size_t A_bytes     = (size_t)N_NODES * KDIM * 2;   // 51,200,000
    const size_t elist_bytes = (size_t)E_EDGES * 4;          //  3,200,000
    const size_t tlist_bytes = (size_t)E_EDGES * 4;          //  3,200,000
    const size_t offs3_pad   = 600064;                       // (NSEG+1)*4 padded
    ushort_t* A      = (ushort_t*)(ws);
    int*      elist  = (int*)(ws + A_bytes);
    int*      tlist  = (int*)(ws + A_bytes + elist_bytes);
    int*      offs3  = (int*)(ws + A_bytes + elist_bytes + tlist_bytes);
    char*     p      = ws + A_bytes + elist_bytes + tlist_bytes + offs3_pad;
    int*      mat    = (int*)p;            p += 50176;       // 12544 ints
    int*      bbase  = (int*)p;            p += 512;
    int*      bstart = (int*)p;            p += 1088;
    ushort_t* Wf1    = (ushort_t*)p;       p += 131072;
    ushort_t* Wf2    = (ushort_t*)p;       p += 131072;
    float*    sc1    = (float*)p;          p += 512;
    float*    sh1    = (float*)p;          p += 512;
    float*    sc2    = (float*)p;          p += 512;
    float*    sh2    = (float*)p;          p += 512;
    ushort_t* H2     = (ushort_t*)p;       p += (size_t)N_NODES * DH * 2;   // 12.8 MB

    // fused pre: build_x + chunk_hist + setup
    pre_kernel<<<PRE_S, 256, 0, stream>>>(x_idx, se, ce, pe, A,
                                          eidx, mat,
                                          W1, root1, W2, root2, Wf1, Wf2,
                                          batch, bstart,
                                          b1, g1, beta1, m1, v1,
                                          b2, g2, beta2, m2, v2,
                                          sc1, sh1, sc2, sh2);

    // chunked counting-sort CSR build
    matscan_kernel<<<1, 1024, 0, stream>>>(mat, bbase, offs3);
    chunk_scatter_kernel<<<NCHUNK, 512, 0, stream>>>(eidx, etype, mat, tlist);
    localsort_kernel<<<NBUCK, 512, 0, stream>>>(tlist, bbase, offs3, elist);

    // ----- layer 1
    agg_kernel<<<N_NODES / 16, 256, 0, stream>>>((const char*)A, offs3, elist, (char*)A);
    gemm_mfma_kernel<<<(N_NODES + 127) / 128, 256, 0, stream>>>(A, Wf1, sc1, sh1,
                                                                A, KDIM, 3 * DH);

    // ----- layer 2
    agg_kernel<<<N_NODES / 16, 256, 0, stream>>>((const char*)A, offs3, elist, (char*)A);
    gemm_mfma_kernel<<<(N_NODES + 127) / 128, 256, 0, stream>>>(A, Wf2, sc2, sh2,
                                                                H2, DH, 0);

    // ----- fused global mean pool + classifier (compact h2)
    pool_cls_kernel<<<BATCHES, 256, 0, stream>>>(H2, bstart, clsW, clsb, out);
}

// Round 13
// 220.643 us; speedup vs baseline: 1.3130x; 1.1385x over previous
//
#include <hip/hip_runtime.h>

#define N_NODES 50000
#define E_EDGES 800000
#define R_REL 3
#define NSEG (N_NODES * R_REL)    // 150000 (dst,rel) segments
#define DH 128
#define KDIM 512                  // A row: [mean_r0 | mean_r1 | mean_r2 | x/h] in bf16
#define ROWB 1024                 // bytes per A row
#define XOFF (3 * DH * 2)         // byte offset of x/h slot (768)
#define BATCHES 256
#define NCLASS 10
#define EPSV 1e-5f

#define BSHIFT 9
#define BNODES 512                // nodes per bucket
#define NBUCK ((N_NODES + BNODES - 1) / BNODES)   // 98
#define SEGB (BNODES * R_REL)     // 1536 segments per bucket
#define CAP 9216                  // LDS sort capacity (mean 8192, sigma ~90)
#define NCHUNK 128
#define CHUNK (E_EDGES / NCHUNK)  // 6250 (exact)
#define MATN (NBUCK * NCHUNK)     // 12544

// pre_kernel block partition
#define PRE_BX 3125               // build_x blocks (N*16/256)
#define PRE_H (PRE_BX + NCHUNK)   // hist blocks end
#define PRE_S (PRE_H + 67)        // setup blocks end

typedef __attribute__((ext_vector_type(8))) short short8v;
typedef __attribute__((ext_vector_type(4))) unsigned uint4v;
typedef __attribute__((ext_vector_type(4))) float float4v;
typedef unsigned short ushort_t;

__device__ __forceinline__ ushort_t f2bf(float f) {
    union { float f; unsigned u; } x; x.f = f;
    unsigned r = x.u + 0x7FFFu + ((x.u >> 16) & 1u);
    return (ushort_t)(r >> 16);
}
__device__ __forceinline__ float bf2f(ushort_t h) {
    union { unsigned u; float f; } x; x.u = ((unsigned)h) << 16;
    return x.f;
}
__device__ __forceinline__ float u2f(unsigned u) {
    union { unsigned u; float f; } x; x.u = u;
    return x.f;
}

// ---------------------------------------------------------------- fused pre: build_x + chunk_hist + setup
__global__ __launch_bounds__(256) void pre_kernel(
        const int* __restrict__ xi, const float* __restrict__ se,
        const float* __restrict__ ce, const float* __restrict__ pe,
        ushort_t* __restrict__ A,
        const int* __restrict__ ei, int* __restrict__ mat,
        const float* __restrict__ W1, const float* __restrict__ root1,
        const float* __restrict__ W2, const float* __restrict__ root2,
        ushort_t* __restrict__ Wf1, ushort_t* __restrict__ Wf2,
        const int* __restrict__ batch, int* __restrict__ bstart,
        const float* __restrict__ b1, const float* __restrict__ g1,
        const float* __restrict__ be1, const float* __restrict__ m1,
        const float* __restrict__ v1,
        const float* __restrict__ b2, const float* __restrict__ g2,
        const float* __restrict__ be2, const float* __restrict__ m2,
        const float* __restrict__ v2,
        float* __restrict__ sc1, float* __restrict__ sh1,
        float* __restrict__ sc2, float* __restrict__ sh2) {
    __shared__ int lh[NBUCK];
    int blk = blockIdx.x, t = threadIdx.x;
    if (blk < PRE_BX) {
        // ---- build x (bf16) into A x-slot
        int tid = blk * 256 + t;
        int node = tid >> 4, c = tid & 15;
        int i0 = xi[node * 3 + 0];
        int i1 = xi[node * 3 + 1];
        int i2 = xi[node * 3 + 2];
        i2 = i2 < 0 ? 0 : (i2 > 24 ? 24 : i2);
        const float4* sa = reinterpret_cast<const float4*>(se + (size_t)i0 * DH + c * 8);
        const float4* sb = reinterpret_cast<const float4*>(ce + (size_t)i1 * DH + c * 8);
        const float4* sp = reinterpret_cast<const float4*>(pe + (size_t)i2 * DH + c * 8);
        short8v o;
        #pragma unroll
        for (int q = 0; q < 2; ++q) {
            float4 a = sa[q], b = sb[q], p = sp[q];
            o[q * 4 + 0] = (short)f2bf(a.x + b.x + p.x);
            o[q * 4 + 1] = (short)f2bf(a.y + b.y + p.y);
            o[q * 4 + 2] = (short)f2bf(a.z + b.z + p.z);
            o[q * 4 + 3] = (short)f2bf(a.w + b.w + p.w);
        }
        *reinterpret_cast<short8v*>(A + (size_t)node * KDIM + 3 * DH + c * 8) = o;
    } else if (blk < PRE_H) {
        // ---- per-(chunk,bucket) histogram
        int ch = blk - PRE_BX;
        if (t < NBUCK) lh[t] = 0;
        __syncthreads();
        int base = ch * CHUNK;
        for (int i = t; i < CHUNK; i += 256)
            atomicAdd(&lh[ei[E_EDGES + base + i] >> BSHIFT], 1);
        __syncthreads();
        if (t < NBUCK) mat[t * NCHUNK + ch] = lh[t];
    } else if (blk < PRE_S) {
        // ---- setup: weight prepack + batch bounds + BN consts
        int tid = (blk - PRE_H) * 256 + t;
        if (tid < 16384) {
            int L = tid >> 13;
            int rem = tid & 8191;
            int l = rem & 63;
            int nt = (rem >> 6) & 7;
            int ks = rem >> 9;
            const float* W = L ? W2 : W1;
            const float* root = L ? root2 : root1;
            ushort_t* dst = (L ? Wf2 : Wf1) + (size_t)rem * 8;
            int col = nt * 16 + (l & 15);
            int kb = ks * 32 + (l >> 4) * 8;
            short8v o;
            #pragma unroll
            for (int j = 0; j < 8; ++j) {
                int k = kb + j;
                float w = (k < 384) ? W[(size_t)k * DH + col]
                                    : root[(size_t)(k - 384) * DH + col];
                o[j] = (short)f2bf(w);
            }
            *reinterpret_cast<short8v*>(dst) = o;
        } else if (tid < 16384 + BATCHES + 1) {
            int b = tid - 16384;
            int lo = 0, hi = N_NODES;
            while (lo < hi) {
                int mid = (lo + hi) >> 1;
                if (batch[mid] < b) lo = mid + 1; else hi = mid;
            }
            bstart[b] = lo;
        } else if (tid < 16384 + 257 + DH) {
            int c = tid - 16384 - 257;
            float s = g1[c] * rsqrtf(v1[c] + EPSV);
            sc1[c] = s;
            sh1[c] = (b1[c] - m1[c]) * s + be1[c];
        } else if (tid < 16384 + 257 + 2 * DH) {
            int c = tid - 16384 - 257 - DH;
            float s = g2[c] * rsqrtf(v2[c] + EPSV);
            sc2[c] = s;
            sh2[c] = (b2[c] - m2[c]) * s + be2[c];
        }
    }
}

// ---------------------------------------------------------------- matrix exclusive scan (bucket-major)
__global__ __launch_bounds__(1024) void matscan_kernel(int* __restrict__ mat,
                                                       int* __restrict__ bbase,
                                                       int* __restrict__ offs3) {
    __shared__ int partial[1024];
    int t = threadIdx.x;
    int buf[13];
    int base = t * 13;
    int s = 0;
    #pragma unroll
    for (int j = 0; j < 13; ++j) {
        int idx = base + j;
        int v = (idx < MATN) ? mat[idx] : 0;
        buf[j] = s;
        s += v;
    }
    partial[t] = s;
    __syncthreads();
    for (int d = 1; d < 1024; d <<= 1) {
        int u = (t >= d) ? partial[t - d] : 0;
        __syncthreads();
        partial[t] += u;
        __syncthreads();
    }
    int off = (t > 0) ? partial[t - 1] : 0;
    #pragma unroll
    for (int j = 0; j < 13; ++j) {
        int idx = base + j;
        if (idx < MATN) mat[idx] = off + buf[j];
    }
    __syncthreads();
    if (t < NBUCK) bbase[t] = mat[t * NCHUNK];
    if (t == 0) { bbase[NBUCK] = E_EDGES; offs3[NSEG] = E_EDGES; }
}

// ---------------------------------------------------------------- chunk counting-sort + coalesced scatter
__global__ __launch_bounds__(512) void chunk_scatter_kernel(const int* __restrict__ ei,
                                                            const int* __restrict__ et,
                                                            const int* __restrict__ mat,
                                                            int* __restrict__ tlist) {
    __shared__ int sorted[CHUNK];
    __shared__ int lh[NBUCK];
    __shared__ int lstart[NBUCK + 1];
    __shared__ int mbase[NBUCK];
    __shared__ int scr[128];
    int t = threadIdx.x, blk = blockIdx.x;
    if (t < NBUCK) { lh[t] = 0; mbase[t] = mat[t * NCHUNK + blk]; }
    __syncthreads();
    int base = blk * CHUNK;
    for (int i = t; i < CHUNK; i += 512)
        atomicAdd(&lh[ei[E_EDGES + base + i] >> BSHIFT], 1);
    __syncthreads();
    if (t < 128) scr[t] = (t < NBUCK) ? lh[t] : 0;
    __syncthreads();
    for (int d = 1; d < 128; d <<= 1) {
        int u = 0;
        if (t < 128 && t >= d) u = scr[t - d];
        __syncthreads();
        if (t < 128) scr[t] += u;
        __syncthreads();
    }
    if (t < NBUCK) lstart[t] = scr[t] - lh[t];
    if (t == NBUCK - 1) lstart[NBUCK] = scr[t];
    __syncthreads();
    if (t < NBUCK) lh[t] = lstart[t];
    __syncthreads();
    for (int i = t; i < CHUNK; i += 512) {
        int e = base + i;
        int src = ei[e];
        int dst = ei[E_EDGES + e];
        int r = et[e];
        int b = dst >> BSHIFT;
        int ls = (dst & (BNODES - 1)) * R_REL + r;
        int p = atomicAdd(&lh[b], 1);
        sorted[p] = (ls << 16) | src;
    }
    __syncthreads();
    for (int i = t; i < CHUNK; i += 512) {
        int lo = 0, hi = NBUCK - 1;
        while (lo < hi) {
            int mid = (lo + hi + 1) >> 1;
            if (lstart[mid] <= i) lo = mid; else hi = mid - 1;
        }
        tlist[mbase[lo] + (i - lstart[lo])] = sorted[i];
    }
}

// ---------------------------------------------------------------- per-bucket local sort by (node,rel)
__global__ __launch_bounds__(512) void localsort_kernel(const int* __restrict__ tlist,
                                                        const int* __restrict__ bbase,
                                                        int* __restrict__ offs3,
                                                        int* __restrict__ elist) {
    __shared__ int hist[SEGB];
    __shared__ int scr[512];
    __shared__ int tl[CAP];
    __shared__ int el[CAP];
    int b = blockIdx.x, t = threadIdx.x;
    int ebeg = bbase[b], eend = bbase[b + 1];
    int cnt = eend - ebeg;
    int segbase = b * SEGB;
    #pragma unroll
    for (int j = 0; j < 3; ++j) hist[t + j * 512] = 0;
    __syncthreads();

    bool fit = (cnt <= CAP);
    if (fit) {
        for (int i = t; i < cnt; i += 512) {
            int pk = tlist[ebeg + i];
            tl[i] = pk;
            atomicAdd(&hist[pk >> 16], 1);
        }
    } else {
        for (int i = t; i < cnt; i += 512)
            atomicAdd(&hist[tlist[ebeg + i] >> 16], 1);
    }
    __syncthreads();
    int h0 = hist[3 * t], h1 = hist[3 * t + 1], h2 = hist[3 * t + 2];
    int s = h0 + h1 + h2;
    scr[t] = s;
    __syncthreads();
    for (int d = 1; d < 512; d <<= 1) {
        int u = (t >= d) ? scr[t - d] : 0;
        __syncthreads();
        scr[t] += u;
        __syncthreads();
    }
    int off = (t > 0) ? scr[t - 1] : 0;
    int e0 = off, e1 = off + h0, e2 = off + h0 + h1;
    {
        int sg = segbase + 3 * t;
        if (sg < NSEG)     offs3[sg]     = ebeg + e0;
        if (sg + 1 < NSEG) offs3[sg + 1] = ebeg + e1;
        if (sg + 2 < NSEG) offs3[sg + 2] = ebeg + e2;
    }
    __syncthreads();
    hist[3 * t] = e0; hist[3 * t + 1] = e1; hist[3 * t + 2] = e2;
    __syncthreads();
    if (fit) {
        for (int i = t; i < cnt; i += 512) {
            int pk = tl[i];
            int pos = atomicAdd(&hist[pk >> 16], 1);
            el[pos] = (pk & 0xFFFF) * ROWB + XOFF;
        }
        __syncthreads();
        for (int i = t; i < cnt; i += 512)
            elist[ebeg + i] = el[i];
    } else {
        for (int i = t; i < cnt; i += 512) {
            int pk = tlist[ebeg + i];
            int pos = atomicAdd(&hist[pk >> 16], 1);
            elist[ebeg + pos] = (pk & 0xFFFF) * ROWB + XOFF;
        }
    }
}

// ---------------------------------------------------------------- gather aggregation: per-rel means
// 16 lanes per node (16B each), 16 nodes per 256-thr block. Unified loop over all 3
// segments, running-sum snapshots at rel boundaries, batch-4 index+gather pipeline.
__global__ __launch_bounds__(256) void agg_kernel(const char* __restrict__ Ab,
                                                  const int* __restrict__ offs3,
                                                  const int* __restrict__ elist,
                                                  char* __restrict__ Aob) {
    int t = threadIdx.x;
    int g = t >> 4, c = t & 15;
    int n = blockIdx.x * 16 + g;              // grid 3125, exact
    int s0 = offs3[3 * n + 0];
    int s1 = offs3[3 * n + 1];
    int s2 = offs3[3 * n + 2];
    int s3 = offs3[3 * n + 3];
    int cb = c * 16;

    float S0 = 0, S1 = 0, S2 = 0, S3 = 0, S4 = 0, S5 = 0, S6 = 0, S7 = 0;
    float p0 = 0, p1 = 0, p2 = 0, p3 = 0, p4 = 0, p5 = 0, p6 = 0, p7 = 0;
    float q0 = 0, q1 = 0, q2 = 0, q3 = 0, q4 = 0, q5 = 0, q6 = 0, q7 = 0;

    #define ACC8(V)                                           \
        S0 += u2f(V[0] << 16); S1 += u2f(V[0] & 0xFFFF0000u); \
        S2 += u2f(V[1] << 16); S3 += u2f(V[1] & 0xFFFF0000u); \
        S4 += u2f(V[2] << 16); S5 += u2f(V[2] & 0xFFFF0000u); \
        S6 += u2f(V[3] << 16); S7 += u2f(V[3] & 0xFFFF0000u);
    #define SNAPCHK(E)                                                              \
        if ((E) == s1) { p0=S0; p1=S1; p2=S2; p3=S3; p4=S4; p5=S5; p6=S6; p7=S7; }  \
        if ((E) == s2) { q0=S0; q1=S1; q2=S2; q3=S3; q4=S4; q5=S5; q6=S6; q7=S7; }

    int i = s0;
    int bend = s0 + ((s3 - s0) & ~3);
    if (i < bend) {
        int j0 = elist[i], j1 = elist[i + 1], j2 = elist[i + 2], j3 = elist[i + 3];
        uint4v g0 = *reinterpret_cast<const uint4v*>(Ab + j0 + cb);
        uint4v g1 = *reinterpret_cast<const uint4v*>(Ab + j1 + cb);
        uint4v g2 = *reinterpret_cast<const uint4v*>(Ab + j2 + cb);
        uint4v g3 = *reinterpret_cast<const uint4v*>(Ab + j3 + cb);
        for (;;) {
            int inx = i + 4;
            bool more = inx < bend;
            uint4v h0, h1, h2, h3;
            if (more) {
                int k0 = elist[inx], k1 = elist[inx + 1], k2 = elist[inx + 2], k3 = elist[inx + 3];
                h0 = *reinterpret_cast<const uint4v*>(Ab + k0 + cb);
                h1 = *reinterpret_cast<const uint4v*>(Ab + k1 + cb);
                h2 = *reinterpret_cast<const uint4v*>(Ab + k2 + cb);
                h3 = *reinterpret_cast<const uint4v*>(Ab + k3 + cb);
            }
            SNAPCHK(i)     ACC8(g0)
            SNAPCHK(i + 1) ACC8(g1)
            SNAPCHK(i + 2) ACC8(g2)
            SNAPCHK(i + 3) ACC8(g3)
            if (!more) break;
            g0 = h0; g1 = h1; g2 = h2; g3 = h3;
            i = inx;
        }
        i = bend;
    }
    for (; i < s3; ++i) {
        int j = elist[i];
        uint4v v = *reinterpret_cast<const uint4v*>(Ab + j + cb);
        SNAPCHK(i)
        ACC8(v)
    }
    if (s1 == s3) { p0=S0; p1=S1; p2=S2; p3=S3; p4=S4; p5=S5; p6=S6; p7=S7; }
    if (s2 == s3) { q0=S0; q1=S1; q2=S2; q3=S3; q4=S4; q5=S5; q6=S6; q7=S7; }
    #undef ACC8
    #undef SNAPCHK

    int c0 = s1 - s0, c1 = s2 - s1, c2 = s3 - s2;
    float i0 = c0 ? 1.f / c0 : 0.f;
    float i1 = c1 ? 1.f / c1 : 0.f;
    float i2 = c2 ? 1.f / c2 : 0.f;
    char* base = Aob + (size_t)n * ROWB + cb;
    uint4v o;
    o[0] = (unsigned)f2bf(p0 * i0) | ((unsigned)f2bf(p1 * i0) << 16);
    o[1] = (unsigned)f2bf(p2 * i0) | ((unsigned)f2bf(p3 * i0) << 16);
    o[2] = (unsigned)f2bf(p4 * i0) | ((unsigned)f2bf(p5 * i0) << 16);
    o[3] = (unsigned)f2bf(p6 * i0) | ((unsigned)f2bf(p7 * i0) << 16);
    *reinterpret_cast<uint4v*>(base + 0 * 256) = o;
    o[0] = (unsigned)f2bf((q0 - p0) * i1) | ((unsigned)f2bf((q1 - p1) * i1) << 16);
    o[1] = (unsigned)f2bf((q2 - p2) * i1) | ((unsigned)f2bf((q3 - p3) * i1) << 16);
    o[2] = (unsigned)f2bf((q4 - p4) * i1) | ((unsigned)f2bf((q5 - p5) * i1) << 16);
    o[3] = (unsigned)f2bf((q6 - p6) * i1) | ((unsigned)f2bf((q7 - p7) * i1) << 16);
    *reinterpret_cast<uint4v*>(base + 1 * 256) = o;
    o[0] = (unsigned)f2bf((S0 - q0) * i2) | ((unsigned)f2bf((S1 - q1) * i2) << 16);
    o[1] = (unsigned)f2bf((S2 - q2) * i2) | ((unsigned)f2bf((S3 - q3) * i2) << 16);
    o[2] = (unsigned)f2bf((S4 - q4) * i2) | ((unsigned)f2bf((S5 - q5) * i2) << 16);
    o[3] = (unsigned)f2bf((S6 - q6) * i2) | ((unsigned)f2bf((S7 - q7) * i2) << 16);
    *reinterpret_cast<uint4v*>(base + 2 * 256) = o;
}

// ---------------------------------------------------------------- MFMA GEMM + BN + ReLU
// 32 rows/block, 4 waves = 2 row-tiles x 2 col-halves; each wave: 16 rows x 64 cols,
// acc = 4 x float4 (16 VGPR). Grid 1563 x 4 waves = ~24 waves/CU for latency hiding.
__global__ __launch_bounds__(256) void gemm_mfma_kernel(const ushort_t* __restrict__ A,
                                                        const ushort_t* __restrict__ Wf,
                                                        const float* __restrict__ sc,
                                                        const float* __restrict__ sh,
                                                        ushort_t* __restrict__ Aout,
                                                        int ostride, int ooff) {
    int w = threadIdx.x >> 6, l = threadIdx.x & 63;
    int tile = w >> 1, chf = w & 1;
    int base = blockIdx.x * 32 + tile * 16;
    int arow = base + (l & 15);
    if (arow >= N_NODES) arow = N_NODES - 1;           // clamp loads; stores guarded
    const short8v* ap = reinterpret_cast<const short8v*>(A + (size_t)arow * KDIM + (l >> 4) * 8);
    const short8v* wf = reinterpret_cast<const short8v*>(Wf) + chf * 256 + l;

    float4v acc[4];
    #pragma unroll
    for (int nt = 0; nt < 4; ++nt) acc[nt] = (float4v){0.f, 0.f, 0.f, 0.f};

    #pragma unroll 4
    for (int ks = 0; ks < 16; ++ks) {
        short8v a = ap[ks * 4];
        const short8v* bp = wf + ks * 512;
        #pragma unroll
        for (int nt = 0; nt < 4; ++nt) {
            short8v b = bp[nt * 64];
            acc[nt] = __builtin_amdgcn_mfma_f32_16x16x32_bf16(a, b, acc[nt], 0, 0, 0);
        }
    }

    int colb = l & 15;
    int rowq = (l >> 4) * 4;
    #pragma unroll
    for (int nt = 0; nt < 4; ++nt) {
        int col = (chf * 4 + nt) * 16 + colb;
        float scv = sc[col], shv = sh[col];
        #pragma unroll
        for (int r = 0; r < 4; ++r) {
            int row = base + rowq + r;
            if (row < N_NODES) {
                float val = fmaxf(acc[nt][r] * scv + shv, 0.f);
                Aout[(size_t)row * ostride + ooff + col] = f2bf(val);
            }
        }
    }
}

// ---------------------------------------------------------------- fused global-mean-pool + classifier
__global__ __launch_bounds__(256) void pool_cls_kernel(
        const ushort_t* __restrict__ h,             // compact [N][DH] bf16
        const int* __restrict__ bstart,
        const float* __restrict__ clsW,
        const float* __restrict__ clsb,
        float* __restrict__ out) {
    __shared__ float hsh[DH];
    int b = blockIdx.x;
    int t = threadIdx.x;
    int c = t & 127;
    int half = t >> 7;
    int beg = bstart[b], end = bstart[b + 1];
    float s = 0.f;
    for (int n = beg + half; n < end; n += 2)
        s += bf2f(h[(size_t)n * DH + c]);
    if (half == 1) hsh[c] = s;
    __syncthreads();
    if (half == 0) {
        float cnt = (float)(end - beg);
        float inv = cnt > 0.f ? 1.f / cnt : 1.f;
        hsh[c] = (s + hsh[c]) * inv;
    }
    __syncthreads();
    if (t < NCLASS) {
        float acc = clsb[t];
        #pragma unroll 16
        for (int d = 0; d < DH; ++d)
            acc += hsh[d] * clsW[d * NCLASS + t];
        out[b * NCLASS + t] = acc;
    }
}

// ---------------------------------------------------------------- launch
extern "C" void kernel_launch(void* const* d_in, const int* in_sizes, int n_in,
                              void* d_out, int out_size, void* d_ws, size_t ws_size,
                              hipStream_t stream) {
    const int*   x_idx  = (const int*)d_in[0];
    const int*   eidx   = (const int*)d_in[1];
    const int*   etype  = (const int*)d_in[2];
    const int*   batch  = (const int*)d_in[3];
    const float* se     = (const float*)d_in[4];
    const float* ce     = (const float*)d_in[5];
    const float* pe     = (const float*)d_in[6];
    const float* W1     = (const float*)d_in[7];
    const float* root1  = (const float*)d_in[8];
    const float* b1     = (const float*)d_in[9];
    const float* g1     = (const float*)d_in[10];
    const float* beta1  = (const float*)d_in[11];
    const float* m1     = (const float*)d_in[12];
    const float* v1     = (const float*)d_in[13];
    const float* W2     = (const float*)d_in[14];
    const float* root2  = (const float*)d_in[15];
    const float* b2     = (const float*)d_in[16];
    const float* g2     = (const float*)d_in[17];
    const float* beta2  = (const float*)d_in[18];
    const float* m2     = (const float*)d_in[19];
    const float* v2     = (const float*)d_in[20];
    const float* clsW   = (const float*)d_in[21];
    const float* clsb   = (const float*)d_in[22];
    float* out = (float*)d_out;

    // workspace layout (16B-aligned blocks)
    char* ws = (char*)d_ws;
    const size_t A_bytes     = (size_t)N_NODES * KDIM * 2;   // 51,200,000
    const size_t elist_bytes = (size_t)E_EDGES * 4;          //  3,200,000
    const size_t tlist_bytes = (size_t)E_EDGES * 4;          //  3,200,000
    const size_t offs3_pad   = 600064;                       // (NSEG+1)*4 padded
    ushort_t* A      = (ushort_t*)(ws);
    int*      elist  = (int*)(ws + A_bytes);
    int*      tlist  = (int*)(ws + A_bytes + elist_bytes);
    int*      offs3  = (int*)(ws + A_bytes + elist_bytes + tlist_bytes);
    char*     p      = ws + A_bytes + elist_bytes + tlist_bytes + offs3_pad;
    int*      mat    = (int*)p;            p += 50176;       // 12544 ints
    int*      bbase  = (int*)p;            p += 512;
    int*      bstart = (int*)p;            p += 1088;
    ushort_t* Wf1    = (ushort_t*)p;       p += 131072;
    ushort_t* Wf2    = (ushort_t*)p;       p += 131072;
    float*    sc1    = (float*)p;          p += 512;
    float*    sh1    = (float*)p;          p += 512;
    float*    sc2    = (float*)p;          p += 512;
    float*    sh2    = (float*)p;          p += 512;
    ushort_t* H2     = (ushort_t*)p;       p += (size_t)N_NODES * DH * 2;   // 12.8 MB

    // fused pre: build_x + chunk_hist + setup
    pre_kernel<<<PRE_S, 256, 0, stream>>>(x_idx, se, ce, pe, A,
                                          eidx, mat,
                                          W1, root1, W2, root2, Wf1, Wf2,
                                          batch, bstart,
                                          b1, g1, beta1, m1, v1,
                                          b2, g2, beta2, m2, v2,
                                          sc1, sh1, sc2, sh2);

    // chunked counting-sort CSR build
    matscan_kernel<<<1, 1024, 0, stream>>>(mat, bbase, offs3);
    chunk_scatter_kernel<<<NCHUNK, 512, 0, stream>>>(eidx, etype, mat, tlist);
    localsort_kernel<<<NBUCK, 512, 0, stream>>>(tlist, bbase, offs3, elist);

    // ----- layer 1
    agg_kernel<<<N_NODES / 16, 256, 0, stream>>>((const char*)A, offs3, elist, (char*)A);
    gemm_mfma_kernel<<<(N_NODES + 31) / 32, 256, 0, stream>>>(A, Wf1, sc1, sh1,
                                                              A, KDIM, 3 * DH);

    // ----- layer 2
    agg_kernel<<<N_NODES / 16, 256, 0, stream>>>((const char*)A, offs3, elist, (char*)A);
    gemm_mfma_kernel<<<(N_NODES + 31) / 32, 256, 0, stream>>>(A, Wf2, sc2, sh2,
                                                              H2, DH, 0);

    // ----- fused global mean pool + classifier (compact h2)
    pool_cls_kernel<<<BATCHES, 256, 0, stream>>>(H2, bstart, clsW, clsb, out);
}